// Round 1
// baseline (790.291 us; speedup 1.0000x reference)
//
#include <hip/hip_runtime.h>
#include <cstdint>
#include <cstddef>

#define NN 100000
#define NE 1600000
#define FD 128

// ---------------- degree histogram ----------------
__global__ void k_hist(const int* __restrict__ dst, int* __restrict__ cnt, int e) {
    int i = blockIdx.x * blockDim.x + threadIdx.x;
    if (i < e) atomicAdd(&cnt[dst[i]], 1);
}

// dis[i] = rsqrt(indeg + 1)  (self-loop adds 1; deg always > 0)
__global__ void k_dis(const int* __restrict__ cnt, float* __restrict__ dis, int n) {
    int i = blockIdx.x * blockDim.x + threadIdx.x;
    if (i < n) dis[i] = rsqrtf((float)(cnt[i] + 1));
}

// ---------------- exclusive scan (3 kernels) ----------------
__global__ __launch_bounds__(1024) void k_scan1(const int* __restrict__ cnt,
                                                int* __restrict__ excl,
                                                int* __restrict__ bsum, int n) {
    __shared__ int sh[1024];
    int i = blockIdx.x * 1024 + threadIdx.x;
    int v = (i < n) ? cnt[i] : 0;
    sh[threadIdx.x] = v;
    __syncthreads();
    for (int off = 1; off < 1024; off <<= 1) {
        int t = (threadIdx.x >= off) ? sh[threadIdx.x - off] : 0;
        __syncthreads();
        sh[threadIdx.x] += t;
        __syncthreads();
    }
    if (i < n) excl[i] = sh[threadIdx.x] - v;   // exclusive
    if (threadIdx.x == 1023) bsum[blockIdx.x] = sh[1023];
}

__global__ void k_scan2(int* __restrict__ bsum, int nb) {
    if (blockIdx.x == 0 && threadIdx.x == 0) {
        int acc = 0;
        for (int b = 0; b < nb; ++b) { int v = bsum[b]; bsum[b] = acc; acc += v; }
    }
}

__global__ void k_scan3(int* __restrict__ excl, const int* __restrict__ bsum,
                        int* __restrict__ cursor, int n, int e) {
    int i = blockIdx.x * blockDim.x + threadIdx.x;
    if (i < n) {
        int v = excl[i] + bsum[i >> 10];
        excl[i] = v;
        cursor[i] = v;
    }
    if (i == 0) excl[n] = e;
}

// ---------------- CSR fill ----------------
__global__ void k_fill(const int* __restrict__ src, const int* __restrict__ dst,
                       int* __restrict__ cursor, int* __restrict__ col, int e) {
    int i = blockIdx.x * blockDim.x + threadIdx.x;
    if (i < e) {
        int d = dst[i];
        int pos = atomicAdd(&cursor[d], 1);
        col[pos] = src[i];
    }
}

// ---------------- GEMM: H[n x 128] = X[n x 128] @ W[128 x 128] ----------------
// BM=64 rows (blockIdx.x), BN=64 cols (blockIdx.y), BK=64 (2 chunks), 256 thr,
// 4x4 microtile per thread. LDS 33.8 KB -> 4 blocks/CU.
__global__ __launch_bounds__(256) void k_gemm(const float* __restrict__ X,
                                              const float* __restrict__ W,
                                              float* __restrict__ H, int n) {
    __shared__ float As[64][68];   // [row][k], pad 68 to spread banks
    __shared__ float Ws[64][64];   // [k][col]
    const int t  = threadIdx.x;
    const int tx = t & 15;         // col group 0..15
    const int ty = t >> 4;         // row group 0..15
    const int rb = blockIdx.x * 64;
    const int cb = blockIdx.y * 64;

    float acc[4][4] = {};

    for (int c = 0; c < 2; ++c) {
        #pragma unroll
        for (int r = 0; r < 4; ++r) {
            int f   = t + 256 * r;        // 0..1023
            int row = f >> 4;             // 0..63
            int kc  = (f & 15) << 2;      // 0..60 step 4
            float4 v = make_float4(0.f, 0.f, 0.f, 0.f);
            int grow = rb + row;
            if (grow < n)
                v = *(const float4*)(X + (size_t)grow * FD + c * 64 + kc);
            *(float4*)&As[row][kc] = v;
            // W tile: k = row index, j4 = kc
            *(float4*)&Ws[row][kc] =
                *(const float4*)(W + (size_t)(c * 64 + row) * FD + cb + kc);
        }
        __syncthreads();
        #pragma unroll 16
        for (int k = 0; k < 64; ++k) {
            float4 b = *(const float4*)&Ws[k][tx * 4];
            float a0 = As[ty * 4 + 0][k];
            float a1 = As[ty * 4 + 1][k];
            float a2 = As[ty * 4 + 2][k];
            float a3 = As[ty * 4 + 3][k];
            acc[0][0] = fmaf(a0, b.x, acc[0][0]);
            acc[0][1] = fmaf(a0, b.y, acc[0][1]);
            acc[0][2] = fmaf(a0, b.z, acc[0][2]);
            acc[0][3] = fmaf(a0, b.w, acc[0][3]);
            acc[1][0] = fmaf(a1, b.x, acc[1][0]);
            acc[1][1] = fmaf(a1, b.y, acc[1][1]);
            acc[1][2] = fmaf(a1, b.z, acc[1][2]);
            acc[1][3] = fmaf(a1, b.w, acc[1][3]);
            acc[2][0] = fmaf(a2, b.x, acc[2][0]);
            acc[2][1] = fmaf(a2, b.y, acc[2][1]);
            acc[2][2] = fmaf(a2, b.z, acc[2][2]);
            acc[2][3] = fmaf(a2, b.w, acc[2][3]);
            acc[3][0] = fmaf(a3, b.x, acc[3][0]);
            acc[3][1] = fmaf(a3, b.y, acc[3][1]);
            acc[3][2] = fmaf(a3, b.z, acc[3][2]);
            acc[3][3] = fmaf(a3, b.w, acc[3][3]);
        }
        __syncthreads();
    }

    #pragma unroll
    for (int i = 0; i < 4; ++i) {
        int grow = rb + ty * 4 + i;
        if (grow < n)
            *(float4*)(H + (size_t)grow * FD + cb + tx * 4) =
                make_float4(acc[i][0], acc[i][1], acc[i][2], acc[i][3]);
    }
}

// ---------------- 128-wide aggregation (gather, wave per node) ----------------
// out[i][:] = relu?( b[:] + dis[i]^2*h[i][:] + sum_e dis[src]*dis[i]*h[src][:] )
template <int RELU>
__global__ __launch_bounds__(256) void k_agg(const float* __restrict__ h,
                                             const float* __restrict__ dis,
                                             const int* __restrict__ rp,
                                             const int* __restrict__ col,
                                             const float* __restrict__ bias,
                                             float* __restrict__ out, int n) {
    int i    = (int)((blockIdx.x * (size_t)blockDim.x + threadIdx.x) >> 6);
    int lane = threadIdx.x & 63;
    if (i >= n) return;
    float di = dis[i];
    float2 acc = ((const float2*)(h + (size_t)i * FD))[lane];
    float w0 = di * di;
    acc.x *= w0; acc.y *= w0;
    int e1 = rp[i + 1];
    for (int e = rp[i]; e < e1; ++e) {
        int s   = col[e];
        float w = dis[s] * di;
        float2 v = ((const float2*)(h + (size_t)s * FD))[lane];
        acc.x = fmaf(w, v.x, acc.x);
        acc.y = fmaf(w, v.y, acc.y);
    }
    float2 b = ((const float2*)bias)[lane];
    acc.x += b.x; acc.y += b.y;
    if (RELU) { acc.x = fmaxf(acc.x, 0.f); acc.y = fmaxf(acc.y, 0.f); }
    ((float2*)(out + (size_t)i * FD))[lane] = acc;
}

// ---------------- layer-3 matvec: h3[i] = dot(h[i][:], W3[:,0]) ----------------
__global__ __launch_bounds__(256) void k_matvec(const float* __restrict__ h,
                                                const float* __restrict__ W3,
                                                float* __restrict__ h3, int n) {
    int i    = (int)((blockIdx.x * (size_t)blockDim.x + threadIdx.x) >> 6);
    int lane = threadIdx.x & 63;
    if (i >= n) return;
    float2 v = ((const float2*)(h + (size_t)i * FD))[lane];
    float2 w = ((const float2*)W3)[lane];
    float s = v.x * w.x + v.y * w.y;
    #pragma unroll
    for (int off = 32; off; off >>= 1) s += __shfl_xor(s, off);
    if (lane == 0) h3[i] = s;
}

// ---------------- scalar aggregation + bias + sigmoid ----------------
__global__ void k_agg1(const float* __restrict__ h3, const float* __restrict__ dis,
                       const int* __restrict__ rp, const int* __restrict__ col,
                       const float* __restrict__ b3, float* __restrict__ out, int n) {
    int i = blockIdx.x * blockDim.x + threadIdx.x;
    if (i >= n) return;
    float di  = dis[i];
    float acc = di * di * h3[i];
    int e1 = rp[i + 1];
    for (int e = rp[i]; e < e1; ++e) {
        int s = col[e];
        acc = fmaf(dis[s] * di, h3[s], acc);
    }
    acc += b3[0];
    out[i] = 1.f / (1.f + expf(-acc));
}

// ---------------- host launch ----------------
static inline size_t alg(size_t x) { return (x + 255) & ~(size_t)255; }

extern "C" void kernel_launch(void* const* d_in, const int* in_sizes, int n_in,
                              void* d_out, int out_size, void* d_ws, size_t ws_size,
                              hipStream_t stream) {
    const float* x   = (const float*)d_in[0];
    const int*   ei  = (const int*)d_in[1];     // [2, E] : src row then dst row
    const float* W1  = (const float*)d_in[2];
    const float* b1  = (const float*)d_in[3];
    const float* W2  = (const float*)d_in[4];
    const float* b2  = (const float*)d_in[5];
    const float* W3  = (const float*)d_in[6];
    const float* b3  = (const float*)d_in[7];
    float*       out = (float*)d_out;

    const int n = NN, e = NE;
    const int* src = ei;
    const int* dst = ei + e;

    char* w = (char*)d_ws;
    float* dis    = (float*)w;  w += alg((size_t)n * 4);
    int*   cnt    = (int*)w;    w += alg((size_t)n * 4);
    int*   rp     = (int*)w;    w += alg((size_t)(n + 1) * 4);
    int*   cursor = (int*)w;    w += alg((size_t)n * 4);
    int*   bsum   = (int*)w;    w += alg((size_t)128 * 4);
    int*   col    = (int*)w;    w += alg((size_t)e * 4);
    float* bufA   = (float*)w;  w += alg((size_t)n * FD * 4);
    float* bufB   = (float*)w;  w += alg((size_t)n * FD * 4);
    float* h3     = (float*)w;  w += alg((size_t)n * 4);

    hipMemsetAsync(cnt, 0, (size_t)n * 4, stream);

    const int B = 256;
    const int gE = (e + B - 1) / B;        // 6250
    const int gN = (n + B - 1) / B;        // 391
    const int nScan = (n + 1023) / 1024;   // 98

    k_hist<<<gE, B, 0, stream>>>(dst, cnt, e);
    k_dis<<<gN, B, 0, stream>>>(cnt, dis, n);
    k_scan1<<<nScan, 1024, 0, stream>>>(cnt, rp, bsum, n);
    k_scan2<<<1, 64, 0, stream>>>(bsum, nScan);
    k_scan3<<<gN, B, 0, stream>>>(rp, bsum, cursor, n, e);
    k_fill<<<gE, B, 0, stream>>>(src, dst, cursor, col, e);

    dim3 gGemm((n + 63) / 64, 2);
    const int gWave = (n * 64 + B - 1) / B;  // wave per node, 4 nodes/block

    // layer 1
    k_gemm<<<gGemm, B, 0, stream>>>(x, W1, bufA, n);
    k_agg<1><<<gWave, B, 0, stream>>>(bufA, dis, rp, col, b1, bufB, n);
    // layer 2
    k_gemm<<<gGemm, B, 0, stream>>>(bufB, W2, bufA, n);
    k_agg<1><<<gWave, B, 0, stream>>>(bufA, dis, rp, col, b2, bufB, n);
    // layer 3
    k_matvec<<<gWave, B, 0, stream>>>(bufB, W3, h3, n);
    k_agg1<<<gN, B, 0, stream>>>(h3, dis, rp, col, b3, out, n);
}

// Round 2
// 641.412 us; speedup vs baseline: 1.2321x; 1.2321x over previous
//
#include <hip/hip_runtime.h>
#include <cstdint>
#include <cstddef>

#define NN 100000
#define NE 1600000
#define FD 128

// ---------------- degree histogram ----------------
__global__ void k_hist(const int* __restrict__ dst, int* __restrict__ cnt, int e) {
    int i = blockIdx.x * blockDim.x + threadIdx.x;
    if (i < e) atomicAdd(&cnt[dst[i]], 1);
}

// dis[i] = rsqrt(indeg + 1)  (self-loop adds 1)
__global__ void k_dis(const int* __restrict__ cnt, float* __restrict__ dis, int n) {
    int i = blockIdx.x * blockDim.x + threadIdx.x;
    if (i < n) dis[i] = rsqrtf((float)(cnt[i] + 1));
}

// ---------------- exclusive scan (3 kernels) ----------------
__global__ __launch_bounds__(1024) void k_scan1(const int* __restrict__ cnt,
                                                int* __restrict__ excl,
                                                int* __restrict__ bsum, int n) {
    __shared__ int sh[1024];
    int i = blockIdx.x * 1024 + threadIdx.x;
    int v = (i < n) ? cnt[i] : 0;
    sh[threadIdx.x] = v;
    __syncthreads();
    for (int off = 1; off < 1024; off <<= 1) {
        int t = (threadIdx.x >= off) ? sh[threadIdx.x - off] : 0;
        __syncthreads();
        sh[threadIdx.x] += t;
        __syncthreads();
    }
    if (i < n) excl[i] = sh[threadIdx.x] - v;   // exclusive
    if (threadIdx.x == 1023) bsum[blockIdx.x] = sh[1023];
}

// parallel exclusive scan of up to 128 block sums (1 block, 128 thr)
__global__ void k_scan2(int* __restrict__ bsum, int nb) {
    __shared__ int sh[128];
    int t = threadIdx.x;
    int v = (t < nb) ? bsum[t] : 0;
    sh[t] = v;
    __syncthreads();
    for (int off = 1; off < 128; off <<= 1) {
        int u = (t >= off) ? sh[t - off] : 0;
        __syncthreads();
        sh[t] += u;
        __syncthreads();
    }
    if (t < nb) bsum[t] = sh[t] - v;   // exclusive block offsets
}

__global__ void k_scan3(int* __restrict__ excl, const int* __restrict__ bsum,
                        int* __restrict__ cursor, int n, int e) {
    int i = blockIdx.x * blockDim.x + threadIdx.x;
    if (i < n) {
        int v = excl[i] + bsum[i >> 10];
        excl[i] = v;
        cursor[i] = v;
    }
    if (i == 0) excl[n] = e;
}

// ---------------- CSR fill ----------------
__global__ void k_fill(const int* __restrict__ src, const int* __restrict__ dst,
                       int* __restrict__ cursor, int* __restrict__ col, int e) {
    int i = blockIdx.x * blockDim.x + threadIdx.x;
    if (i < e) {
        int d = dst[i];
        int pos = atomicAdd(&cursor[d], 1);
        col[pos] = src[i];
    }
}

// ---------------- GEMM: H[n x 128] = X[n x 128] @ W[128 x 128] ----------------
// BM=64, BN=64, BK=64 (2 chunks), 256 thr, 4x4 microtile.
// A tile stored transposed [k][row] so the A fragment is one ds_read_b128.
__global__ __launch_bounds__(256) void k_gemm(const float* __restrict__ X,
                                              const float* __restrict__ W,
                                              float* __restrict__ H, int n) {
    __shared__ float At[64][68];   // [k][row], pad to spread banks
    __shared__ float Ws[64][64];   // [k][col]
    const int t  = threadIdx.x;
    const int tx = t & 15;
    const int ty = t >> 4;
    const int rb = blockIdx.x * 64;
    const int cb = blockIdx.y * 64;

    float acc[4][4] = {};

    for (int c = 0; c < 2; ++c) {
        #pragma unroll
        for (int r = 0; r < 4; ++r) {
            int f   = t + 256 * r;        // 0..1023
            int row = f >> 4;             // 0..63
            int kc  = (f & 15) << 2;      // 0..60 step 4
            float4 v = make_float4(0.f, 0.f, 0.f, 0.f);
            int grow = rb + row;
            if (grow < n)
                v = *(const float4*)(X + (size_t)grow * FD + c * 64 + kc);
            At[kc + 0][row] = v.x;
            At[kc + 1][row] = v.y;
            At[kc + 2][row] = v.z;
            At[kc + 3][row] = v.w;
            *(float4*)&Ws[row][kc] =
                *(const float4*)(W + (size_t)(c * 64 + row) * FD + cb + kc);
        }
        __syncthreads();
        #pragma unroll 8
        for (int k = 0; k < 64; ++k) {
            float4 a = *(const float4*)&At[k][ty * 4];
            float4 b = *(const float4*)&Ws[k][tx * 4];
            acc[0][0] = fmaf(a.x, b.x, acc[0][0]);
            acc[0][1] = fmaf(a.x, b.y, acc[0][1]);
            acc[0][2] = fmaf(a.x, b.z, acc[0][2]);
            acc[0][3] = fmaf(a.x, b.w, acc[0][3]);
            acc[1][0] = fmaf(a.y, b.x, acc[1][0]);
            acc[1][1] = fmaf(a.y, b.y, acc[1][1]);
            acc[1][2] = fmaf(a.y, b.z, acc[1][2]);
            acc[1][3] = fmaf(a.y, b.w, acc[1][3]);
            acc[2][0] = fmaf(a.z, b.x, acc[2][0]);
            acc[2][1] = fmaf(a.z, b.y, acc[2][1]);
            acc[2][2] = fmaf(a.z, b.z, acc[2][2]);
            acc[2][3] = fmaf(a.z, b.w, acc[2][3]);
            acc[3][0] = fmaf(a.w, b.x, acc[3][0]);
            acc[3][1] = fmaf(a.w, b.y, acc[3][1]);
            acc[3][2] = fmaf(a.w, b.z, acc[3][2]);
            acc[3][3] = fmaf(a.w, b.w, acc[3][3]);
        }
        __syncthreads();
    }

    #pragma unroll
    for (int i = 0; i < 4; ++i) {
        int grow = rb + ty * 4 + i;
        if (grow < n)
            *(float4*)(H + (size_t)grow * FD + cb + tx * 4) =
                make_float4(acc[i][0], acc[i][1], acc[i][2], acc[i][3]);
    }
}

// ---------------- 128-wide aggregation (gather, wave per node) ----------------
// MODE 0: out[i][:] = relu( b[:] + dis[i]^2*h[i][:] + sum dis[s]*dis[i]*h[s][:] )
// MODE 1: same + fused layer-3 matvec: h3[i] = dot(relu_row, W3)
// Lanes cooperatively preload <=64 col/dis per chunk, then broadcast via shfl
// and issue 8 independent row loads per step (ILP for latency hiding).
template <int MODE>
__global__ __launch_bounds__(256) void k_agg(const float* __restrict__ h,
                                             const float* __restrict__ dis,
                                             const int* __restrict__ rp,
                                             const int* __restrict__ col,
                                             const float* __restrict__ bias,
                                             float* __restrict__ out, int n) {
    int i    = (int)((blockIdx.x * (size_t)blockDim.x + threadIdx.x) >> 6);
    int lane = threadIdx.x & 63;
    if (i >= n) return;
    float di = dis[i];
    float2 acc = ((const float2*)(h + (size_t)i * FD))[lane];
    float w0 = di * di;
    acc.x *= w0; acc.y *= w0;
    const int e0 = rp[i], e1 = rp[i + 1];
    for (int base = e0; base < e1; base += 64) {
        int m = e1 - base; if (m > 64) m = 64;
        int s = 0; float w = 0.f;
        if (lane < m) { s = col[base + lane]; w = dis[s] * di; }
        int j = 0;
        for (; j + 8 <= m; j += 8) {
            int ss[8]; float ww[8]; float2 vv[8];
            #pragma unroll
            for (int q = 0; q < 8; ++q) { ss[q] = __shfl(s, j + q); ww[q] = __shfl(w, j + q); }
            #pragma unroll
            for (int q = 0; q < 8; ++q)
                vv[q] = ((const float2*)(h + (size_t)ss[q] * FD))[lane];
            #pragma unroll
            for (int q = 0; q < 8; ++q) {
                acc.x = fmaf(ww[q], vv[q].x, acc.x);
                acc.y = fmaf(ww[q], vv[q].y, acc.y);
            }
        }
        for (; j < m; ++j) {
            int sj = __shfl(s, j); float wj = __shfl(w, j);
            float2 v = ((const float2*)(h + (size_t)sj * FD))[lane];
            acc.x = fmaf(wj, v.x, acc.x);
            acc.y = fmaf(wj, v.y, acc.y);
        }
    }
    float2 b = ((const float2*)bias)[lane];
    acc.x += b.x; acc.y += b.y;
    acc.x = fmaxf(acc.x, 0.f); acc.y = fmaxf(acc.y, 0.f);
    if (MODE == 0) {
        ((float2*)(out + (size_t)i * FD))[lane] = acc;
    } else {
        // fused matvec with W3 [128]
        float2 w3 = ((const float2*)bias)[lane + 64];  // unused slot trick? no:
        // (bias ptr carries b2; W3 passed via out? keep it simple: W3 in 'out'?)
        // -- replaced below by separate pointer; see k_agg_mv.
    }
}

// layer-2 aggregation with fused W3 matvec: writes scalar h3[i]
__global__ __launch_bounds__(256) void k_agg_mv(const float* __restrict__ h,
                                                const float* __restrict__ dis,
                                                const int* __restrict__ rp,
                                                const int* __restrict__ col,
                                                const float* __restrict__ bias,
                                                const float* __restrict__ W3,
                                                float* __restrict__ h3, int n) {
    int i    = (int)((blockIdx.x * (size_t)blockDim.x + threadIdx.x) >> 6);
    int lane = threadIdx.x & 63;
    if (i >= n) return;
    float di = dis[i];
    float2 acc = ((const float2*)(h + (size_t)i * FD))[lane];
    float w0 = di * di;
    acc.x *= w0; acc.y *= w0;
    const int e0 = rp[i], e1 = rp[i + 1];
    for (int base = e0; base < e1; base += 64) {
        int m = e1 - base; if (m > 64) m = 64;
        int s = 0; float w = 0.f;
        if (lane < m) { s = col[base + lane]; w = dis[s] * di; }
        int j = 0;
        for (; j + 8 <= m; j += 8) {
            int ss[8]; float ww[8]; float2 vv[8];
            #pragma unroll
            for (int q = 0; q < 8; ++q) { ss[q] = __shfl(s, j + q); ww[q] = __shfl(w, j + q); }
            #pragma unroll
            for (int q = 0; q < 8; ++q)
                vv[q] = ((const float2*)(h + (size_t)ss[q] * FD))[lane];
            #pragma unroll
            for (int q = 0; q < 8; ++q) {
                acc.x = fmaf(ww[q], vv[q].x, acc.x);
                acc.y = fmaf(ww[q], vv[q].y, acc.y);
            }
        }
        for (; j < m; ++j) {
            int sj = __shfl(s, j); float wj = __shfl(w, j);
            float2 v = ((const float2*)(h + (size_t)sj * FD))[lane];
            acc.x = fmaf(wj, v.x, acc.x);
            acc.y = fmaf(wj, v.y, acc.y);
        }
    }
    float2 b = ((const float2*)bias)[lane];
    acc.x = fmaxf(acc.x + b.x, 0.f);
    acc.y = fmaxf(acc.y + b.y, 0.f);
    float2 w3 = ((const float2*)W3)[lane];
    float sdot = acc.x * w3.x + acc.y * w3.y;
    #pragma unroll
    for (int off = 32; off; off >>= 1) sdot += __shfl_xor(sdot, off);
    if (lane == 0) h3[i] = sdot;
}

// ---------------- scalar aggregation + bias + sigmoid (wave per node) ----------
__global__ __launch_bounds__(256) void k_agg1(const float* __restrict__ h3,
                                              const float* __restrict__ dis,
                                              const int* __restrict__ rp,
                                              const int* __restrict__ col,
                                              const float* __restrict__ b3,
                                              float* __restrict__ out, int n) {
    int i    = (int)((blockIdx.x * (size_t)blockDim.x + threadIdx.x) >> 6);
    int lane = threadIdx.x & 63;
    if (i >= n) return;
    float di  = dis[i];
    float acc = (lane == 0) ? di * di * h3[i] : 0.f;
    const int e0 = rp[i], e1 = rp[i + 1];
    for (int base = e0 + lane; base < e1; base += 64) {
        int s = col[base];
        acc = fmaf(dis[s] * di, h3[s], acc);
    }
    #pragma unroll
    for (int off = 32; off; off >>= 1) acc += __shfl_xor(acc, off);
    if (lane == 0) {
        float v = acc + b3[0];
        out[i] = 1.f / (1.f + expf(-v));
    }
}

// ---------------- host launch ----------------
static inline size_t alg(size_t x) { return (x + 255) & ~(size_t)255; }

extern "C" void kernel_launch(void* const* d_in, const int* in_sizes, int n_in,
                              void* d_out, int out_size, void* d_ws, size_t ws_size,
                              hipStream_t stream) {
    const float* x   = (const float*)d_in[0];
    const int*   ei  = (const int*)d_in[1];     // [2, E]
    const float* W1  = (const float*)d_in[2];
    const float* b1  = (const float*)d_in[3];
    const float* W2  = (const float*)d_in[4];
    const float* b2  = (const float*)d_in[5];
    const float* W3  = (const float*)d_in[6];
    const float* b3  = (const float*)d_in[7];
    float*       out = (float*)d_out;

    const int n = NN, e = NE;
    const int* src = ei;
    const int* dst = ei + e;

    char* w = (char*)d_ws;
    float* dis    = (float*)w;  w += alg((size_t)n * 4);
    int*   cnt    = (int*)w;    w += alg((size_t)n * 4);
    int*   rp     = (int*)w;    w += alg((size_t)(n + 1) * 4);
    int*   cursor = (int*)w;    w += alg((size_t)n * 4);
    int*   bsum   = (int*)w;    w += alg((size_t)128 * 4);
    int*   col    = (int*)w;    w += alg((size_t)e * 4);
    float* bufA   = (float*)w;  w += alg((size_t)n * FD * 4);
    float* bufB   = (float*)w;  w += alg((size_t)n * FD * 4);
    float* h3     = (float*)w;  w += alg((size_t)n * 4);

    hipMemsetAsync(cnt, 0, (size_t)n * 4, stream);

    const int B = 256;
    const int gE = (e + B - 1) / B;
    const int gN = (n + B - 1) / B;
    const int nScan = (n + 1023) / 1024;   // 98

    k_hist<<<gE, B, 0, stream>>>(dst, cnt, e);
    k_dis<<<gN, B, 0, stream>>>(cnt, dis, n);
    k_scan1<<<nScan, 1024, 0, stream>>>(cnt, rp, bsum, n);
    k_scan2<<<1, 128, 0, stream>>>(bsum, nScan);
    k_scan3<<<gN, B, 0, stream>>>(rp, bsum, cursor, n, e);
    k_fill<<<gE, B, 0, stream>>>(src, dst, cursor, col, e);

    dim3 gGemm((n + 63) / 64, 2);
    const int gWave = (n * 64 + B - 1) / B;  // wave per node

    // layer 1
    k_gemm<<<gGemm, B, 0, stream>>>(x, W1, bufA, n);
    k_agg<0><<<gWave, B, 0, stream>>>(bufA, dis, rp, col, b1, bufB, n);
    // layer 2 (+ fused layer-3 matvec)
    k_gemm<<<gGemm, B, 0, stream>>>(bufB, W2, bufA, n);
    k_agg_mv<<<gWave, B, 0, stream>>>(bufA, dis, rp, col, b2, W3, h3, n);
    // layer 3
    k_agg1<<<gWave, B, 0, stream>>>(h3, dis, rp, col, b3, out, n);
}

// Round 3
// 597.160 us; speedup vs baseline: 1.3234x; 1.0741x over previous
//
#include <hip/hip_runtime.h>
#include <cstdint>
#include <cstddef>

#define NN 100000
#define NE 1600000
#define FD 128
#define NXCD 8
#define RNODES ((NN + NXCD - 1) / NXCD)   // 12500 nodes per XCD range

// ---------------- degree histogram ----------------
__global__ void k_hist(const int* __restrict__ dst, int* __restrict__ cnt, int e) {
    int i = blockIdx.x * blockDim.x + threadIdx.x;
    if (i < e) atomicAdd(&cnt[dst[i]], 1);
}

// ---------------- exclusive scan (3 kernels) ----------------
__global__ __launch_bounds__(1024) void k_scan1(const int* __restrict__ cnt,
                                                int* __restrict__ excl,
                                                int* __restrict__ bsum, int n) {
    __shared__ int sh[1024];
    int i = blockIdx.x * 1024 + threadIdx.x;
    int v = (i < n) ? cnt[i] : 0;
    sh[threadIdx.x] = v;
    __syncthreads();
    for (int off = 1; off < 1024; off <<= 1) {
        int t = (threadIdx.x >= off) ? sh[threadIdx.x - off] : 0;
        __syncthreads();
        sh[threadIdx.x] += t;
        __syncthreads();
    }
    if (i < n) excl[i] = sh[threadIdx.x] - v;   // exclusive
    if (threadIdx.x == 1023) bsum[blockIdx.x] = sh[1023];
}

// parallel exclusive scan of up to 128 block sums (1 block, 128 thr)
__global__ void k_scan2(int* __restrict__ bsum, int nb) {
    __shared__ int sh[128];
    int t = threadIdx.x;
    int v = (t < nb) ? bsum[t] : 0;
    sh[t] = v;
    __syncthreads();
    for (int off = 1; off < 128; off <<= 1) {
        int u = (t >= off) ? sh[t - off] : 0;
        __syncthreads();
        sh[t] += u;
        __syncthreads();
    }
    if (t < nb) bsum[t] = sh[t] - v;   // exclusive block offsets
}

// finalize row_ptr, init cursor, and compute dis = rsqrt(deg+1) (fused k_dis)
__global__ void k_scan3(int* __restrict__ excl, const int* __restrict__ bsum,
                        int* __restrict__ cursor, const int* __restrict__ cnt,
                        float* __restrict__ dis, int n, int e) {
    int i = blockIdx.x * blockDim.x + threadIdx.x;
    if (i < n) {
        int v = excl[i] + bsum[i >> 10];
        excl[i] = v;
        cursor[i] = v;
        dis[i] = rsqrtf((float)(cnt[i] + 1));
    }
    if (i == 0) excl[n] = e;
}

// ---------------- CSR fill, XCD-partitioned by dst range ----------------
// Each chunk of 1024 edges is scanned by 8 blocks (one per XCD via bid&7);
// a block only handles edges whose dst lies in its XCD's 12500-node range,
// so col[] writes land in a contiguous ~XCD-local slab that stays L2-resident
// until fully populated (kills the 16x scattered-write amplification).
__global__ __launch_bounds__(256) void k_fill(const int* __restrict__ src,
                                              const int* __restrict__ dst,
                                              int* __restrict__ cursor,
                                              int* __restrict__ col, int e) {
    const int xcd   = blockIdx.x & 7;
    const int chunk = blockIdx.x >> 3;
    const int lo = xcd * RNODES;
    const int hi = lo + RNODES;
    const int base = chunk * 1024 + threadIdx.x * 4;
    if (base >= e) return;                 // e % 4 == 0 -> int4 load safe
    int4 d4 = *(const int4*)(dst + base);
    #pragma unroll
    for (int j = 0; j < 4; ++j) {
        int d = (&d4.x)[j];
        if (d >= lo && d < hi) {
            int s   = src[base + j];
            int pos = atomicAdd(&cursor[d], 1);
            col[pos] = s;
        }
    }
}

// ---------------- GEMM: H[n x 128] = X[n x 128] @ W[128 x 128] ----------------
__global__ __launch_bounds__(256) void k_gemm(const float* __restrict__ X,
                                              const float* __restrict__ W,
                                              float* __restrict__ H, int n) {
    __shared__ float At[64][68];   // [k][row], pad to spread banks
    __shared__ float Ws[64][64];   // [k][col]
    const int t  = threadIdx.x;
    const int tx = t & 15;
    const int ty = t >> 4;
    const int rb = blockIdx.x * 64;
    const int cb = blockIdx.y * 64;

    float acc[4][4] = {};

    for (int c = 0; c < 2; ++c) {
        #pragma unroll
        for (int r = 0; r < 4; ++r) {
            int f   = t + 256 * r;        // 0..1023
            int row = f >> 4;             // 0..63
            int kc  = (f & 15) << 2;      // 0..60 step 4
            float4 v = make_float4(0.f, 0.f, 0.f, 0.f);
            int grow = rb + row;
            if (grow < n)
                v = *(const float4*)(X + (size_t)grow * FD + c * 64 + kc);
            At[kc + 0][row] = v.x;
            At[kc + 1][row] = v.y;
            At[kc + 2][row] = v.z;
            At[kc + 3][row] = v.w;
            *(float4*)&Ws[row][kc] =
                *(const float4*)(W + (size_t)(c * 64 + row) * FD + cb + kc);
        }
        __syncthreads();
        #pragma unroll 8
        for (int k = 0; k < 64; ++k) {
            float4 a = *(const float4*)&At[k][ty * 4];
            float4 b = *(const float4*)&Ws[k][tx * 4];
            acc[0][0] = fmaf(a.x, b.x, acc[0][0]);
            acc[0][1] = fmaf(a.x, b.y, acc[0][1]);
            acc[0][2] = fmaf(a.x, b.z, acc[0][2]);
            acc[0][3] = fmaf(a.x, b.w, acc[0][3]);
            acc[1][0] = fmaf(a.y, b.x, acc[1][0]);
            acc[1][1] = fmaf(a.y, b.y, acc[1][1]);
            acc[1][2] = fmaf(a.y, b.z, acc[1][2]);
            acc[1][3] = fmaf(a.y, b.w, acc[1][3]);
            acc[2][0] = fmaf(a.z, b.x, acc[2][0]);
            acc[2][1] = fmaf(a.z, b.y, acc[2][1]);
            acc[2][2] = fmaf(a.z, b.z, acc[2][2]);
            acc[2][3] = fmaf(a.z, b.w, acc[2][3]);
            acc[3][0] = fmaf(a.w, b.x, acc[3][0]);
            acc[3][1] = fmaf(a.w, b.y, acc[3][1]);
            acc[3][2] = fmaf(a.w, b.z, acc[3][2]);
            acc[3][3] = fmaf(a.w, b.w, acc[3][3]);
        }
        __syncthreads();
    }

    #pragma unroll
    for (int i = 0; i < 4; ++i) {
        int grow = rb + ty * 4 + i;
        if (grow < n)
            *(float4*)(H + (size_t)grow * FD + cb + tx * 4) =
                make_float4(acc[i][0], acc[i][1], acc[i][2], acc[i][3]);
    }
}

// ---------------- 128-wide aggregation (gather, wave per node) ----------------
// out[i][:] = relu( b[:] + dis[i]^2*h[i][:] + sum dis[s]*dis[i]*h[s][:] )
// Lanes cooperatively preload <=64 col/dis per chunk, broadcast via shfl,
// issue 8 independent row loads per step (MLP for latency hiding).
__global__ __launch_bounds__(256) void k_agg(const float* __restrict__ h,
                                             const float* __restrict__ dis,
                                             const int* __restrict__ rp,
                                             const int* __restrict__ col,
                                             const float* __restrict__ bias,
                                             float* __restrict__ out, int n) {
    int i    = (int)((blockIdx.x * (size_t)blockDim.x + threadIdx.x) >> 6);
    int lane = threadIdx.x & 63;
    if (i >= n) return;
    float di = dis[i];
    float2 acc = ((const float2*)(h + (size_t)i * FD))[lane];
    float w0 = di * di;
    acc.x *= w0; acc.y *= w0;
    const int e0 = rp[i], e1 = rp[i + 1];
    for (int base = e0; base < e1; base += 64) {
        int m = e1 - base; if (m > 64) m = 64;
        int s = 0; float w = 0.f;
        if (lane < m) { s = col[base + lane]; w = dis[s] * di; }
        int j = 0;
        for (; j + 8 <= m; j += 8) {
            int ss[8]; float ww[8]; float2 vv[8];
            #pragma unroll
            for (int q = 0; q < 8; ++q) { ss[q] = __shfl(s, j + q); ww[q] = __shfl(w, j + q); }
            #pragma unroll
            for (int q = 0; q < 8; ++q)
                vv[q] = ((const float2*)(h + (size_t)ss[q] * FD))[lane];
            #pragma unroll
            for (int q = 0; q < 8; ++q) {
                acc.x = fmaf(ww[q], vv[q].x, acc.x);
                acc.y = fmaf(ww[q], vv[q].y, acc.y);
            }
        }
        for (; j < m; ++j) {
            int sj = __shfl(s, j); float wj = __shfl(w, j);
            float2 v = ((const float2*)(h + (size_t)sj * FD))[lane];
            acc.x = fmaf(wj, v.x, acc.x);
            acc.y = fmaf(wj, v.y, acc.y);
        }
    }
    float2 b = ((const float2*)bias)[lane];
    acc.x = fmaxf(acc.x + b.x, 0.f);
    acc.y = fmaxf(acc.y + b.y, 0.f);
    ((float2*)(out + (size_t)i * FD))[lane] = acc;
}

// layer-2 aggregation with fused W3 matvec: writes scalar h3[i]
__global__ __launch_bounds__(256) void k_agg_mv(const float* __restrict__ h,
                                                const float* __restrict__ dis,
                                                const int* __restrict__ rp,
                                                const int* __restrict__ col,
                                                const float* __restrict__ bias,
                                                const float* __restrict__ W3,
                                                float* __restrict__ h3, int n) {
    int i    = (int)((blockIdx.x * (size_t)blockDim.x + threadIdx.x) >> 6);
    int lane = threadIdx.x & 63;
    if (i >= n) return;
    float di = dis[i];
    float2 acc = ((const float2*)(h + (size_t)i * FD))[lane];
    float w0 = di * di;
    acc.x *= w0; acc.y *= w0;
    const int e0 = rp[i], e1 = rp[i + 1];
    for (int base = e0; base < e1; base += 64) {
        int m = e1 - base; if (m > 64) m = 64;
        int s = 0; float w = 0.f;
        if (lane < m) { s = col[base + lane]; w = dis[s] * di; }
        int j = 0;
        for (; j + 8 <= m; j += 8) {
            int ss[8]; float ww[8]; float2 vv[8];
            #pragma unroll
            for (int q = 0; q < 8; ++q) { ss[q] = __shfl(s, j + q); ww[q] = __shfl(w, j + q); }
            #pragma unroll
            for (int q = 0; q < 8; ++q)
                vv[q] = ((const float2*)(h + (size_t)ss[q] * FD))[lane];
            #pragma unroll
            for (int q = 0; q < 8; ++q) {
                acc.x = fmaf(ww[q], vv[q].x, acc.x);
                acc.y = fmaf(ww[q], vv[q].y, acc.y);
            }
        }
        for (; j < m; ++j) {
            int sj = __shfl(s, j); float wj = __shfl(w, j);
            float2 v = ((const float2*)(h + (size_t)sj * FD))[lane];
            acc.x = fmaf(wj, v.x, acc.x);
            acc.y = fmaf(wj, v.y, acc.y);
        }
    }
    float2 b = ((const float2*)bias)[lane];
    acc.x = fmaxf(acc.x + b.x, 0.f);
    acc.y = fmaxf(acc.y + b.y, 0.f);
    float2 w3 = ((const float2*)W3)[lane];
    float sdot = acc.x * w3.x + acc.y * w3.y;
    #pragma unroll
    for (int off = 32; off; off >>= 1) sdot += __shfl_xor(sdot, off);
    if (lane == 0) h3[i] = sdot;
}

// ---------------- scalar aggregation + bias + sigmoid (wave per node) ----------
__global__ __launch_bounds__(256) void k_agg1(const float* __restrict__ h3,
                                              const float* __restrict__ dis,
                                              const int* __restrict__ rp,
                                              const int* __restrict__ col,
                                              const float* __restrict__ b3,
                                              float* __restrict__ out, int n) {
    int i    = (int)((blockIdx.x * (size_t)blockDim.x + threadIdx.x) >> 6);
    int lane = threadIdx.x & 63;
    if (i >= n) return;
    float di  = dis[i];
    float acc = (lane == 0) ? di * di * h3[i] : 0.f;
    const int e0 = rp[i], e1 = rp[i + 1];
    for (int base = e0 + lane; base < e1; base += 64) {
        int s = col[base];
        acc = fmaf(dis[s] * di, h3[s], acc);
    }
    #pragma unroll
    for (int off = 32; off; off >>= 1) acc += __shfl_xor(acc, off);
    if (lane == 0) {
        float v = acc + b3[0];
        out[i] = 1.f / (1.f + expf(-v));
    }
}

// ---------------- host launch ----------------
static inline size_t alg(size_t x) { return (x + 255) & ~(size_t)255; }

extern "C" void kernel_launch(void* const* d_in, const int* in_sizes, int n_in,
                              void* d_out, int out_size, void* d_ws, size_t ws_size,
                              hipStream_t stream) {
    const float* x   = (const float*)d_in[0];
    const int*   ei  = (const int*)d_in[1];     // [2, E]
    const float* W1  = (const float*)d_in[2];
    const float* b1  = (const float*)d_in[3];
    const float* W2  = (const float*)d_in[4];
    const float* b2  = (const float*)d_in[5];
    const float* W3  = (const float*)d_in[6];
    const float* b3  = (const float*)d_in[7];
    float*       out = (float*)d_out;

    const int n = NN, e = NE;
    const int* src = ei;
    const int* dst = ei + e;

    char* w = (char*)d_ws;
    float* dis    = (float*)w;  w += alg((size_t)n * 4);
    int*   cnt    = (int*)w;    w += alg((size_t)n * 4);
    int*   rp     = (int*)w;    w += alg((size_t)(n + 1) * 4);
    int*   cursor = (int*)w;    w += alg((size_t)n * 4);
    int*   bsum   = (int*)w;    w += alg((size_t)128 * 4);
    int*   col    = (int*)w;    w += alg((size_t)e * 4);
    float* bufA   = (float*)w;  w += alg((size_t)n * FD * 4);
    float* bufB   = (float*)w;  w += alg((size_t)n * FD * 4);
    float* h3     = (float*)w;  w += alg((size_t)n * 4);

    hipMemsetAsync(cnt, 0, (size_t)n * 4, stream);

    const int B = 256;
    const int gE = (e + B - 1) / B;
    const int gN = (n + B - 1) / B;
    const int nScan = (n + 1023) / 1024;   // 98

    k_hist<<<gE, B, 0, stream>>>(dst, cnt, e);
    k_scan1<<<nScan, 1024, 0, stream>>>(cnt, rp, bsum, n);
    k_scan2<<<1, 128, 0, stream>>>(bsum, nScan);
    k_scan3<<<gN, B, 0, stream>>>(rp, bsum, cursor, cnt, dis, n, e);

    const int nChunk = (e + 1023) / 1024;  // 1563
    k_fill<<<nChunk * NXCD, B, 0, stream>>>(src, dst, cursor, col, e);

    dim3 gGemm((n + 63) / 64, 2);
    const int gWave = (n * 64 + B - 1) / B;  // wave per node

    // layer 1
    k_gemm<<<gGemm, B, 0, stream>>>(x, W1, bufA, n);
    k_agg<<<gWave, B, 0, stream>>>(bufA, dis, rp, col, b1, bufB, n);
    // layer 2 (+ fused layer-3 matvec)
    k_gemm<<<gGemm, B, 0, stream>>>(bufB, W2, bufA, n);
    k_agg_mv<<<gWave, B, 0, stream>>>(bufA, dis, rp, col, b2, W3, h3, n);
    // layer 3
    k_agg1<<<gWave, B, 0, stream>>>(h3, dis, rp, col, b3, out, n);
}

// Round 4
// 593.592 us; speedup vs baseline: 1.3314x; 1.0060x over previous
//
#include <hip/hip_runtime.h>
#include <cstdint>
#include <cstddef>

#define NN 100000
#define NE 1600000
#define FD 128
#define NXCD 8
#define RNODES ((NN + NXCD - 1) / NXCD)   // 12500 nodes per XCD range

// ---------------- degree histogram, XCD-partitioned by dst range ----------
__global__ __launch_bounds__(256) void k_hist(const int* __restrict__ dst,
                                              int* __restrict__ cnt, int e) {
    const int xcd   = blockIdx.x & 7;
    const int chunk = blockIdx.x >> 3;
    const int lo = xcd * RNODES;
    const int hi = lo + RNODES;
    const int base = chunk * 1024 + threadIdx.x * 4;
    if (base >= e) return;                 // e % 4 == 0
    int4 d4 = *(const int4*)(dst + base);
    #pragma unroll
    for (int j = 0; j < 4; ++j) {
        int d = (&d4.x)[j];
        if (d >= lo && d < hi) atomicAdd(&cnt[d], 1);
    }
}

// ---------------- exclusive scan (3 kernels) ----------------
__global__ __launch_bounds__(1024) void k_scan1(const int* __restrict__ cnt,
                                                int* __restrict__ excl,
                                                int* __restrict__ bsum, int n) {
    __shared__ int sh[1024];
    int i = blockIdx.x * 1024 + threadIdx.x;
    int v = (i < n) ? cnt[i] : 0;
    sh[threadIdx.x] = v;
    __syncthreads();
    for (int off = 1; off < 1024; off <<= 1) {
        int t = (threadIdx.x >= off) ? sh[threadIdx.x - off] : 0;
        __syncthreads();
        sh[threadIdx.x] += t;
        __syncthreads();
    }
    if (i < n) excl[i] = sh[threadIdx.x] - v;   // exclusive
    if (threadIdx.x == 1023) bsum[blockIdx.x] = sh[1023];
}

__global__ void k_scan2(int* __restrict__ bsum, int nb) {
    __shared__ int sh[128];
    int t = threadIdx.x;
    int v = (t < nb) ? bsum[t] : 0;
    sh[t] = v;
    __syncthreads();
    for (int off = 1; off < 128; off <<= 1) {
        int u = (t >= off) ? sh[t - off] : 0;
        __syncthreads();
        sh[t] += u;
        __syncthreads();
    }
    if (t < nb) bsum[t] = sh[t] - v;   // exclusive block offsets
}

// finalize row_ptr, init cursor, compute dis = rsqrt(deg+1)
__global__ void k_scan3(int* __restrict__ excl, const int* __restrict__ bsum,
                        int* __restrict__ cursor, const int* __restrict__ cnt,
                        float* __restrict__ dis, int n, int e) {
    int i = blockIdx.x * blockDim.x + threadIdx.x;
    if (i < n) {
        int v = excl[i] + bsum[i >> 10];
        excl[i] = v;
        cursor[i] = v;
        dis[i] = rsqrtf((float)(cnt[i] + 1));
    }
    if (i == 0) excl[n] = e;
}

// ---------------- CSR fill + fused edge weight, XCD-partitioned ------------
// wedge[pos] = dis[src]*dis[dst]; dis is 400 KB -> L2-resident per XCD.
__global__ __launch_bounds__(256) void k_fill(const int* __restrict__ src,
                                              const int* __restrict__ dst,
                                              int* __restrict__ cursor,
                                              int* __restrict__ col,
                                              float* __restrict__ wedge,
                                              const float* __restrict__ dis, int e) {
    const int xcd   = blockIdx.x & 7;
    const int chunk = blockIdx.x >> 3;
    const int lo = xcd * RNODES;
    const int hi = lo + RNODES;
    const int base = chunk * 1024 + threadIdx.x * 4;
    if (base >= e) return;                 // e % 4 == 0
    int4 d4 = *(const int4*)(dst + base);
    #pragma unroll
    for (int j = 0; j < 4; ++j) {
        int d = (&d4.x)[j];
        if (d >= lo && d < hi) {
            int s   = src[base + j];
            int pos = atomicAdd(&cursor[d], 1);
            col[pos]   = s;
            wedge[pos] = dis[s] * dis[d];
        }
    }
}

// ---------------- GEMM: H[n x 128] = X[n x 128] @ W[128 x 128] ----------------
__global__ __launch_bounds__(256) void k_gemm(const float* __restrict__ X,
                                              const float* __restrict__ W,
                                              float* __restrict__ H, int n) {
    __shared__ float At[64][68];   // [k][row], pad to spread banks
    __shared__ float Ws[64][64];   // [k][col]
    const int t  = threadIdx.x;
    const int tx = t & 15;
    const int ty = t >> 4;
    const int rb = blockIdx.x * 64;
    const int cb = blockIdx.y * 64;

    float acc[4][4] = {};

    for (int c = 0; c < 2; ++c) {
        #pragma unroll
        for (int r = 0; r < 4; ++r) {
            int f   = t + 256 * r;        // 0..1023
            int row = f >> 4;             // 0..63
            int kc  = (f & 15) << 2;      // 0..60 step 4
            float4 v = make_float4(0.f, 0.f, 0.f, 0.f);
            int grow = rb + row;
            if (grow < n)
                v = *(const float4*)(X + (size_t)grow * FD + c * 64 + kc);
            At[kc + 0][row] = v.x;
            At[kc + 1][row] = v.y;
            At[kc + 2][row] = v.z;
            At[kc + 3][row] = v.w;
            *(float4*)&Ws[row][kc] =
                *(const float4*)(W + (size_t)(c * 64 + row) * FD + cb + kc);
        }
        __syncthreads();
        #pragma unroll 8
        for (int k = 0; k < 64; ++k) {
            float4 a = *(const float4*)&At[k][ty * 4];
            float4 b = *(const float4*)&Ws[k][tx * 4];
            acc[0][0] = fmaf(a.x, b.x, acc[0][0]);
            acc[0][1] = fmaf(a.x, b.y, acc[0][1]);
            acc[0][2] = fmaf(a.x, b.z, acc[0][2]);
            acc[0][3] = fmaf(a.x, b.w, acc[0][3]);
            acc[1][0] = fmaf(a.y, b.x, acc[1][0]);
            acc[1][1] = fmaf(a.y, b.y, acc[1][1]);
            acc[1][2] = fmaf(a.y, b.z, acc[1][2]);
            acc[1][3] = fmaf(a.y, b.w, acc[1][3]);
            acc[2][0] = fmaf(a.z, b.x, acc[2][0]);
            acc[2][1] = fmaf(a.z, b.y, acc[2][1]);
            acc[2][2] = fmaf(a.z, b.z, acc[2][2]);
            acc[2][3] = fmaf(a.z, b.w, acc[2][3]);
            acc[3][0] = fmaf(a.w, b.x, acc[3][0]);
            acc[3][1] = fmaf(a.w, b.y, acc[3][1]);
            acc[3][2] = fmaf(a.w, b.z, acc[3][2]);
            acc[3][3] = fmaf(a.w, b.w, acc[3][3]);
        }
        __syncthreads();
    }

    #pragma unroll
    for (int i = 0; i < 4; ++i) {
        int grow = rb + ty * 4 + i;
        if (grow < n)
            *(float4*)(H + (size_t)grow * FD + cb + tx * 4) =
                make_float4(acc[i][0], acc[i][1], acc[i][2], acc[i][3]);
    }
}

// ---------------- 128-wide aggregation (gather, wave per node) ----------------
// Edge metadata (col, wedge) read via wave-uniform SCALAR loads
// (readfirstlane-established uniformity), software-pipelined one group ahead;
// 8 independent 512B row loads in flight per group.
// MODE 0: writes relu row to out.  MODE 1: fused dot with W3 -> out[i] scalar.
template <int MODE>
__global__ __launch_bounds__(256) void k_agg(const float* __restrict__ h,
                                             const float* __restrict__ dis,
                                             const int* __restrict__ rp,
                                             const int* __restrict__ col,
                                             const float* __restrict__ wedge,
                                             const float* __restrict__ bias,
                                             const float* __restrict__ W3,
                                             float* __restrict__ out, int n) {
    int wid  = (int)((blockIdx.x * (size_t)blockDim.x + threadIdx.x) >> 6);
    int lane = threadIdx.x & 63;
    int i = __builtin_amdgcn_readfirstlane(wid);
    if (i >= n) return;
    float di = dis[i];
    float2 acc = ((const float2*)(h + (size_t)i * FD))[lane];
    float w0 = di * di;
    acc.x *= w0; acc.y *= w0;
    const int e0 = rp[i], e1 = rp[i + 1];

    const int nfull = (e1 - e0) >> 3;
    int j = e0;
    int sA[8]; float wA[8];
    if (nfull > 0) {
        #pragma unroll
        for (int q = 0; q < 8; ++q) { sA[q] = col[j + q]; wA[q] = wedge[j + q]; }
    }
    for (int g = 0; g < nfull; ++g) {
        int sB[8]; float wB[8];
        const int jn = j + 8;
        if (g + 1 < nfull) {
            #pragma unroll
            for (int q = 0; q < 8; ++q) { sB[q] = col[jn + q]; wB[q] = wedge[jn + q]; }
        }
        float2 vv[8];
        #pragma unroll
        for (int q = 0; q < 8; ++q)
            vv[q] = ((const float2*)(h + (size_t)sA[q] * FD))[lane];
        #pragma unroll
        for (int q = 0; q < 8; ++q) {
            acc.x = fmaf(wA[q], vv[q].x, acc.x);
            acc.y = fmaf(wA[q], vv[q].y, acc.y);
        }
        #pragma unroll
        for (int q = 0; q < 8; ++q) { sA[q] = sB[q]; wA[q] = wB[q]; }
        j = jn;
    }
    for (; j < e1; ++j) {                 // tail < 8 edges
        int s = col[j]; float w = wedge[j];
        float2 v = ((const float2*)(h + (size_t)s * FD))[lane];
        acc.x = fmaf(w, v.x, acc.x);
        acc.y = fmaf(w, v.y, acc.y);
    }

    float2 b = ((const float2*)bias)[lane];
    acc.x = fmaxf(acc.x + b.x, 0.f);
    acc.y = fmaxf(acc.y + b.y, 0.f);
    if (MODE == 0) {
        ((float2*)(out + (size_t)i * FD))[lane] = acc;
    } else {
        float2 w3 = ((const float2*)W3)[lane];
        float sdot = acc.x * w3.x + acc.y * w3.y;
        #pragma unroll
        for (int off = 32; off; off >>= 1) sdot += __shfl_xor(sdot, off);
        if (lane == 0) out[i] = sdot;
    }
}

// ---------------- scalar aggregation + bias + sigmoid (wave per node) ----------
__global__ __launch_bounds__(256) void k_agg1(const float* __restrict__ h3,
                                              const float* __restrict__ dis,
                                              const int* __restrict__ rp,
                                              const int* __restrict__ col,
                                              const float* __restrict__ wedge,
                                              const float* __restrict__ b3,
                                              float* __restrict__ out, int n) {
    int i    = (int)((blockIdx.x * (size_t)blockDim.x + threadIdx.x) >> 6);
    int lane = threadIdx.x & 63;
    if (i >= n) return;
    float di  = dis[i];
    float acc = (lane == 0) ? di * di * h3[i] : 0.f;
    const int e0 = rp[i], e1 = rp[i + 1];
    for (int base = e0 + lane; base < e1; base += 64) {
        acc = fmaf(wedge[base], h3[col[base]], acc);
    }
    #pragma unroll
    for (int off = 32; off; off >>= 1) acc += __shfl_xor(acc, off);
    if (lane == 0) {
        float v = acc + b3[0];
        out[i] = 1.f / (1.f + expf(-v));
    }
}

// ---------------- host launch ----------------
static inline size_t alg(size_t x) { return (x + 255) & ~(size_t)255; }

extern "C" void kernel_launch(void* const* d_in, const int* in_sizes, int n_in,
                              void* d_out, int out_size, void* d_ws, size_t ws_size,
                              hipStream_t stream) {
    const float* x   = (const float*)d_in[0];
    const int*   ei  = (const int*)d_in[1];     // [2, E]
    const float* W1  = (const float*)d_in[2];
    const float* b1  = (const float*)d_in[3];
    const float* W2  = (const float*)d_in[4];
    const float* b2  = (const float*)d_in[5];
    const float* W3  = (const float*)d_in[6];
    const float* b3  = (const float*)d_in[7];
    float*       out = (float*)d_out;

    const int n = NN, e = NE;
    const int* src = ei;
    const int* dst = ei + e;

    char* w = (char*)d_ws;
    float* dis    = (float*)w;  w += alg((size_t)n * 4);
    int*   cnt    = (int*)w;    w += alg((size_t)n * 4);
    int*   rp     = (int*)w;    w += alg((size_t)(n + 1) * 4);
    int*   cursor = (int*)w;    w += alg((size_t)n * 4);
    int*   bsum   = (int*)w;    w += alg((size_t)128 * 4);
    int*   col    = (int*)w;    w += alg((size_t)e * 4);
    float* wedge  = (float*)w;  w += alg((size_t)e * 4);
    float* bufA   = (float*)w;  w += alg((size_t)n * FD * 4);
    float* bufB   = (float*)w;  w += alg((size_t)n * FD * 4);
    float* h3     = (float*)w;  w += alg((size_t)n * 4);

    hipMemsetAsync(cnt, 0, (size_t)n * 4, stream);

    const int B = 256;
    const int gN = (n + B - 1) / B;
    const int nScan = (n + 1023) / 1024;   // 98
    const int nChunk = (e + 1023) / 1024;  // 1563

    k_hist<<<nChunk * NXCD, B, 0, stream>>>(dst, cnt, e);
    k_scan1<<<nScan, 1024, 0, stream>>>(cnt, rp, bsum, n);
    k_scan2<<<1, 128, 0, stream>>>(bsum, nScan);
    k_scan3<<<gN, B, 0, stream>>>(rp, bsum, cursor, cnt, dis, n, e);
    k_fill<<<nChunk * NXCD, B, 0, stream>>>(src, dst, cursor, col, wedge, dis, e);

    dim3 gGemm((n + 63) / 64, 2);
    const int gWave = (n * 64 + B - 1) / B;  // wave per node

    // layer 1
    k_gemm<<<gGemm, B, 0, stream>>>(x, W1, bufA, n);
    k_agg<0><<<gWave, B, 0, stream>>>(bufA, dis, rp, col, wedge, b1, W3, bufB, n);
    // layer 2 (+ fused layer-3 matvec)
    k_gemm<<<gGemm, B, 0, stream>>>(bufB, W2, bufA, n);
    k_agg<1><<<gWave, B, 0, stream>>>(bufA, dis, rp, col, wedge, b2, W3, h3, n);
    // layer 3
    k_agg1<<<gWave, B, 0, stream>>>(h3, dis, rp, col, wedge, b3, out, n);
}

// Round 5
// 548.772 us; speedup vs baseline: 1.4401x; 1.0817x over previous
//
#include <hip/hip_runtime.h>
#include <cstdint>
#include <cstddef>

#define NN 100000
#define NE 1600000
#define FD 128
#define NXCD 8
#define RNODES ((NN + NXCD - 1) / NXCD)   // 12500 nodes per XCD range

// ---- bf16 helpers (RNE), storage-only precision reduction ----
__device__ __forceinline__ float bf_lo(uint32_t u) { return __uint_as_float(u << 16); }
__device__ __forceinline__ float bf_hi(uint32_t u) { return __uint_as_float(u & 0xffff0000u); }
__device__ __forceinline__ uint32_t bf_pack(float a, float b) {
    uint32_t ua = __float_as_uint(a), ub = __float_as_uint(b);
    ua += 0x7fffu + ((ua >> 16) & 1u);
    ub += 0x7fffu + ((ub >> 16) & 1u);
    return (ua >> 16) | (ub & 0xffff0000u);
}

// ---------------- degree histogram, XCD-partitioned by dst range ----------
__global__ __launch_bounds__(256) void k_hist(const int* __restrict__ dst,
                                              int* __restrict__ cnt, int e) {
    const int xcd   = blockIdx.x & 7;
    const int chunk = blockIdx.x >> 3;
    const int lo = xcd * RNODES;
    const int hi = lo + RNODES;
    const int base = chunk * 1024 + threadIdx.x * 4;
    if (base >= e) return;                 // e % 4 == 0
    int4 d4 = *(const int4*)(dst + base);
    #pragma unroll
    for (int j = 0; j < 4; ++j) {
        int d = (&d4.x)[j];
        if (d >= lo && d < hi) atomicAdd(&cnt[d], 1);
    }
}

// ---------------- exclusive scan (3 kernels) ----------------
__global__ __launch_bounds__(1024) void k_scan1(const int* __restrict__ cnt,
                                                int* __restrict__ excl,
                                                int* __restrict__ bsum, int n) {
    __shared__ int sh[1024];
    int i = blockIdx.x * 1024 + threadIdx.x;
    int v = (i < n) ? cnt[i] : 0;
    sh[threadIdx.x] = v;
    __syncthreads();
    for (int off = 1; off < 1024; off <<= 1) {
        int t = (threadIdx.x >= off) ? sh[threadIdx.x - off] : 0;
        __syncthreads();
        sh[threadIdx.x] += t;
        __syncthreads();
    }
    if (i < n) excl[i] = sh[threadIdx.x] - v;   // exclusive
    if (threadIdx.x == 1023) bsum[blockIdx.x] = sh[1023];
}

__global__ void k_scan2(int* __restrict__ bsum, int nb) {
    __shared__ int sh[128];
    int t = threadIdx.x;
    int v = (t < nb) ? bsum[t] : 0;
    sh[t] = v;
    __syncthreads();
    for (int off = 1; off < 128; off <<= 1) {
        int u = (t >= off) ? sh[t - off] : 0;
        __syncthreads();
        sh[t] += u;
        __syncthreads();
    }
    if (t < nb) bsum[t] = sh[t] - v;   // exclusive block offsets
}

// finalize row_ptr, init cursor, compute dis = rsqrt(deg+1)
__global__ void k_scan3(int* __restrict__ excl, const int* __restrict__ bsum,
                        int* __restrict__ cursor, const int* __restrict__ cnt,
                        float* __restrict__ dis, int n, int e) {
    int i = blockIdx.x * blockDim.x + threadIdx.x;
    if (i < n) {
        int v = excl[i] + bsum[i >> 10];
        excl[i] = v;
        cursor[i] = v;
        dis[i] = rsqrtf((float)(cnt[i] + 1));
    }
    if (i == 0) excl[n] = e;
}

// ---------------- CSR fill + fused edge weight, XCD-partitioned ------------
__global__ __launch_bounds__(256) void k_fill(const int* __restrict__ src,
                                              const int* __restrict__ dst,
                                              int* __restrict__ cursor,
                                              int* __restrict__ col,
                                              float* __restrict__ wedge,
                                              const float* __restrict__ dis, int e) {
    const int xcd   = blockIdx.x & 7;
    const int chunk = blockIdx.x >> 3;
    const int lo = xcd * RNODES;
    const int hi = lo + RNODES;
    const int base = chunk * 1024 + threadIdx.x * 4;
    if (base >= e) return;                 // e % 4 == 0
    int4 d4 = *(const int4*)(dst + base);
    #pragma unroll
    for (int j = 0; j < 4; ++j) {
        int d = (&d4.x)[j];
        if (d >= lo && d < hi) {
            int s   = src[base + j];
            int pos = atomicAdd(&cursor[d], 1);
            col[pos]   = s;
            wedge[pos] = dis[s] * dis[d];
        }
    }
}

// ---------------- GEMM: H[n x 128] = X[n x 128] @ W[128 x 128] -> bf16 -------
// TIN = float (layer 1 input) or ushort bf16x1 (layer 2 input).
template <typename TIN>
__global__ __launch_bounds__(256) void k_gemm(const TIN* __restrict__ X,
                                              const float* __restrict__ W,
                                              unsigned short* __restrict__ H, int n) {
    __shared__ float At[64][68];   // [k][row]
    __shared__ float Ws[64][64];   // [k][col]
    const int t  = threadIdx.x;
    const int tx = t & 15;
    const int ty = t >> 4;
    const int rb = blockIdx.x * 64;
    const int cb = blockIdx.y * 64;

    float acc[4][4] = {};

    for (int c = 0; c < 2; ++c) {
        #pragma unroll
        for (int r = 0; r < 4; ++r) {
            int f   = t + 256 * r;        // 0..1023
            int row = f >> 4;             // 0..63
            int kc  = (f & 15) << 2;      // 0..60 step 4
            int grow = rb + row;
            float4 v = make_float4(0.f, 0.f, 0.f, 0.f);
            if (grow < n) {
                if constexpr (sizeof(TIN) == 4) {
                    v = *(const float4*)((const float*)X + (size_t)grow * FD + c * 64 + kc);
                } else {
                    uint2 p = *(const uint2*)((const unsigned short*)X + (size_t)grow * FD + c * 64 + kc);
                    v.x = bf_lo(p.x); v.y = bf_hi(p.x);
                    v.z = bf_lo(p.y); v.w = bf_hi(p.y);
                }
            }
            At[kc + 0][row] = v.x;
            At[kc + 1][row] = v.y;
            At[kc + 2][row] = v.z;
            At[kc + 3][row] = v.w;
            *(float4*)&Ws[row][kc] =
                *(const float4*)(W + (size_t)(c * 64 + row) * FD + cb + kc);
        }
        __syncthreads();
        #pragma unroll 8
        for (int k = 0; k < 64; ++k) {
            float4 a = *(const float4*)&At[k][ty * 4];
            float4 b = *(const float4*)&Ws[k][tx * 4];
            acc[0][0] = fmaf(a.x, b.x, acc[0][0]);
            acc[0][1] = fmaf(a.x, b.y, acc[0][1]);
            acc[0][2] = fmaf(a.x, b.z, acc[0][2]);
            acc[0][3] = fmaf(a.x, b.w, acc[0][3]);
            acc[1][0] = fmaf(a.y, b.x, acc[1][0]);
            acc[1][1] = fmaf(a.y, b.y, acc[1][1]);
            acc[1][2] = fmaf(a.y, b.z, acc[1][2]);
            acc[1][3] = fmaf(a.y, b.w, acc[1][3]);
            acc[2][0] = fmaf(a.z, b.x, acc[2][0]);
            acc[2][1] = fmaf(a.z, b.y, acc[2][1]);
            acc[2][2] = fmaf(a.z, b.z, acc[2][2]);
            acc[2][3] = fmaf(a.z, b.w, acc[2][3]);
            acc[3][0] = fmaf(a.w, b.x, acc[3][0]);
            acc[3][1] = fmaf(a.w, b.y, acc[3][1]);
            acc[3][2] = fmaf(a.w, b.z, acc[3][2]);
            acc[3][3] = fmaf(a.w, b.w, acc[3][3]);
        }
        __syncthreads();
    }

    #pragma unroll
    for (int i = 0; i < 4; ++i) {
        int grow = rb + ty * 4 + i;
        if (grow < n) {
            uint2 p;
            p.x = bf_pack(acc[i][0], acc[i][1]);
            p.y = bf_pack(acc[i][2], acc[i][3]);
            *(uint2*)(H + (size_t)grow * FD + cb + tx * 4) = p;
        }
    }
}

// ---------------- 128-wide aggregation over bf16 rows (wave per node) --------
// Edge metadata via wave-uniform scalar loads; 16 independent 256B row loads
// in flight per group, software-pipelined one group ahead. fp32 accumulation.
// MODE 0: writes relu row (bf16) to out.  MODE 1: fused dot with W3 -> outf[i].
template <int MODE>
__global__ __launch_bounds__(256) void k_agg(const unsigned short* __restrict__ h,
                                             const float* __restrict__ dis,
                                             const int* __restrict__ rp,
                                             const int* __restrict__ col,
                                             const float* __restrict__ wedge,
                                             const float* __restrict__ bias,
                                             const float* __restrict__ W3,
                                             unsigned short* __restrict__ out,
                                             float* __restrict__ outf, int n) {
    int wid  = (int)((blockIdx.x * (size_t)blockDim.x + threadIdx.x) >> 6);
    int lane = threadIdx.x & 63;
    int i = __builtin_amdgcn_readfirstlane(wid);
    if (i >= n) return;
    float di = dis[i];
    float w0 = di * di;
    uint32_t su = ((const uint32_t*)(h + (size_t)i * FD))[lane];
    float2 acc;
    acc.x = bf_lo(su) * w0;
    acc.y = bf_hi(su) * w0;
    const int e0 = rp[i], e1 = rp[i + 1];

    const int nfull = (e1 - e0) >> 4;
    int j = e0;
    int sA[16]; float wA[16];
    if (nfull > 0) {
        #pragma unroll
        for (int q = 0; q < 16; ++q) { sA[q] = col[j + q]; wA[q] = wedge[j + q]; }
    }
    for (int g = 0; g < nfull; ++g) {
        int sB[16]; float wB[16];
        const int jn = j + 16;
        if (g + 1 < nfull) {
            #pragma unroll
            for (int q = 0; q < 16; ++q) { sB[q] = col[jn + q]; wB[q] = wedge[jn + q]; }
        }
        uint32_t vv[16];
        #pragma unroll
        for (int q = 0; q < 16; ++q)
            vv[q] = ((const uint32_t*)(h + (size_t)sA[q] * FD))[lane];
        #pragma unroll
        for (int q = 0; q < 16; ++q) {
            acc.x = fmaf(wA[q], bf_lo(vv[q]), acc.x);
            acc.y = fmaf(wA[q], bf_hi(vv[q]), acc.y);
        }
        #pragma unroll
        for (int q = 0; q < 16; ++q) { sA[q] = sB[q]; wA[q] = wB[q]; }
        j = jn;
    }
    for (; j < e1; ++j) {                 // tail < 16 edges
        uint32_t u = ((const uint32_t*)(h + (size_t)col[j] * FD))[lane];
        float w = wedge[j];
        acc.x = fmaf(w, bf_lo(u), acc.x);
        acc.y = fmaf(w, bf_hi(u), acc.y);
    }

    float2 b = ((const float2*)bias)[lane];
    acc.x = fmaxf(acc.x + b.x, 0.f);
    acc.y = fmaxf(acc.y + b.y, 0.f);
    if (MODE == 0) {
        ((uint32_t*)(out + (size_t)i * FD))[lane] = bf_pack(acc.x, acc.y);
    } else {
        float2 w3 = ((const float2*)W3)[lane];
        float sdot = acc.x * w3.x + acc.y * w3.y;
        #pragma unroll
        for (int off = 32; off; off >>= 1) sdot += __shfl_xor(sdot, off);
        if (lane == 0) outf[i] = sdot;
    }
}

// ---------------- scalar aggregation + bias + sigmoid (wave per node) ----------
__global__ __launch_bounds__(256) void k_agg1(const float* __restrict__ h3,
                                              const float* __restrict__ dis,
                                              const int* __restrict__ rp,
                                              const int* __restrict__ col,
                                              const float* __restrict__ wedge,
                                              const float* __restrict__ b3,
                                              float* __restrict__ out, int n) {
    int i    = (int)((blockIdx.x * (size_t)blockDim.x + threadIdx.x) >> 6);
    int lane = threadIdx.x & 63;
    if (i >= n) return;
    float di  = dis[i];
    float acc = (lane == 0) ? di * di * h3[i] : 0.f;
    const int e0 = rp[i], e1 = rp[i + 1];
    for (int base = e0 + lane; base < e1; base += 64) {
        acc = fmaf(wedge[base], h3[col[base]], acc);
    }
    #pragma unroll
    for (int off = 32; off; off >>= 1) acc += __shfl_xor(acc, off);
    if (lane == 0) {
        float v = acc + b3[0];
        out[i] = 1.f / (1.f + expf(-v));
    }
}

// ---------------- host launch ----------------
static inline size_t alg(size_t x) { return (x + 255) & ~(size_t)255; }

extern "C" void kernel_launch(void* const* d_in, const int* in_sizes, int n_in,
                              void* d_out, int out_size, void* d_ws, size_t ws_size,
                              hipStream_t stream) {
    const float* x   = (const float*)d_in[0];
    const int*   ei  = (const int*)d_in[1];     // [2, E]
    const float* W1  = (const float*)d_in[2];
    const float* b1  = (const float*)d_in[3];
    const float* W2  = (const float*)d_in[4];
    const float* b2  = (const float*)d_in[5];
    const float* W3  = (const float*)d_in[6];
    const float* b3  = (const float*)d_in[7];
    float*       out = (float*)d_out;

    const int n = NN, e = NE;
    const int* src = ei;
    const int* dst = ei + e;

    char* w = (char*)d_ws;
    float* dis    = (float*)w;  w += alg((size_t)n * 4);
    int*   cnt    = (int*)w;    w += alg((size_t)n * 4);
    int*   rp     = (int*)w;    w += alg((size_t)(n + 1) * 4);
    int*   cursor = (int*)w;    w += alg((size_t)n * 4);
    int*   bsum   = (int*)w;    w += alg((size_t)128 * 4);
    int*   col    = (int*)w;    w += alg((size_t)e * 4);
    float* wedge  = (float*)w;  w += alg((size_t)e * 4);
    unsigned short* bufA = (unsigned short*)w; w += alg((size_t)n * FD * 2);
    unsigned short* bufB = (unsigned short*)w; w += alg((size_t)n * FD * 2);
    float* h3     = (float*)w;  w += alg((size_t)n * 4);

    hipMemsetAsync(cnt, 0, (size_t)n * 4, stream);

    const int B = 256;
    const int gN = (n + B - 1) / B;
    const int nScan = (n + 1023) / 1024;   // 98
    const int nChunk = (e + 1023) / 1024;  // 1563

    k_hist<<<nChunk * NXCD, B, 0, stream>>>(dst, cnt, e);
    k_scan1<<<nScan, 1024, 0, stream>>>(cnt, rp, bsum, n);
    k_scan2<<<1, 128, 0, stream>>>(bsum, nScan);
    k_scan3<<<gN, B, 0, stream>>>(rp, bsum, cursor, cnt, dis, n, e);
    k_fill<<<nChunk * NXCD, B, 0, stream>>>(src, dst, cursor, col, wedge, dis, e);

    dim3 gGemm((n + 63) / 64, 2);
    const int gWave = (n * 64 + B - 1) / B;  // wave per node

    // layer 1
    k_gemm<float><<<gGemm, B, 0, stream>>>(x, W1, bufA, n);
    k_agg<0><<<gWave, B, 0, stream>>>(bufA, dis, rp, col, wedge, b1, W3, bufB, h3, n);
    // layer 2 (+ fused layer-3 matvec)
    k_gemm<unsigned short><<<gGemm, B, 0, stream>>>(bufB, W2, bufA, n);
    k_agg<1><<<gWave, B, 0, stream>>>(bufA, dis, rp, col, wedge, b2, W3, bufB, h3, n);
    // layer 3
    k_agg1<<<gWave, B, 0, stream>>>(h3, dis, rp, col, wedge, b3, out, n);
}

// Round 6
// 517.598 us; speedup vs baseline: 1.5268x; 1.0602x over previous
//
#include <hip/hip_runtime.h>
#include <cstdint>
#include <cstddef>

#define NN 100000
#define NE 1600000
#define FD 128
#define NXCD 8
#define RNODES ((NN + NXCD - 1) / NXCD)   // 12500 nodes per XCD range

// ---- bf16 helpers (RNE), storage-only precision reduction ----
__device__ __forceinline__ float bf_lo(uint32_t u) { return __uint_as_float(u << 16); }
__device__ __forceinline__ float bf_hi(uint32_t u) { return __uint_as_float(u & 0xffff0000u); }
__device__ __forceinline__ uint32_t bf_pack(float a, float b) {
    uint32_t ua = __float_as_uint(a), ub = __float_as_uint(b);
    ua += 0x7fffu + ((ua >> 16) & 1u);
    ub += 0x7fffu + ((ub >> 16) & 1u);
    return (ua >> 16) | (ub & 0xffff0000u);
}

// ---------------- degree histogram, XCD-partitioned by dst range ----------
__global__ __launch_bounds__(256) void k_hist(const int* __restrict__ dst,
                                              int* __restrict__ cnt, int e) {
    const int xcd   = blockIdx.x & 7;
    const int chunk = blockIdx.x >> 3;
    const int lo = xcd * RNODES;
    const int hi = lo + RNODES;
    const int base = chunk * 1024 + threadIdx.x * 4;
    if (base >= e) return;                 // e % 4 == 0
    int4 d4 = *(const int4*)(dst + base);
    #pragma unroll
    for (int j = 0; j < 4; ++j) {
        int d = (&d4.x)[j];
        if (d >= lo && d < hi) atomicAdd(&cnt[d], 1);
    }
}

// ---------------- exclusive scan (3 kernels) ----------------
__global__ __launch_bounds__(1024) void k_scan1(const int* __restrict__ cnt,
                                                int* __restrict__ excl,
                                                int* __restrict__ bsum, int n) {
    __shared__ int sh[1024];
    int i = blockIdx.x * 1024 + threadIdx.x;
    int v = (i < n) ? cnt[i] : 0;
    sh[threadIdx.x] = v;
    __syncthreads();
    for (int off = 1; off < 1024; off <<= 1) {
        int t = (threadIdx.x >= off) ? sh[threadIdx.x - off] : 0;
        __syncthreads();
        sh[threadIdx.x] += t;
        __syncthreads();
    }
    if (i < n) excl[i] = sh[threadIdx.x] - v;   // exclusive
    if (threadIdx.x == 1023) bsum[blockIdx.x] = sh[1023];
}

__global__ void k_scan2(int* __restrict__ bsum, int nb) {
    __shared__ int sh[128];
    int t = threadIdx.x;
    int v = (t < nb) ? bsum[t] : 0;
    sh[t] = v;
    __syncthreads();
    for (int off = 1; off < 128; off <<= 1) {
        int u = (t >= off) ? sh[t - off] : 0;
        __syncthreads();
        sh[t] += u;
        __syncthreads();
    }
    if (t < nb) bsum[t] = sh[t] - v;   // exclusive block offsets
}

// finalize row_ptr, init cursor, compute dis = rsqrt(deg+1)
__global__ void k_scan3(int* __restrict__ excl, const int* __restrict__ bsum,
                        int* __restrict__ cursor, const int* __restrict__ cnt,
                        float* __restrict__ dis, int n, int e) {
    int i = blockIdx.x * blockDim.x + threadIdx.x;
    if (i < n) {
        int v = excl[i] + bsum[i >> 10];
        excl[i] = v;
        cursor[i] = v;
        dis[i] = rsqrtf((float)(cnt[i] + 1));
    }
    if (i == 0) excl[n] = e;
}

// ---------------- CSR fill + fused edge weight, XCD-partitioned ------------
__global__ __launch_bounds__(256) void k_fill(const int* __restrict__ src,
                                              const int* __restrict__ dst,
                                              int* __restrict__ cursor,
                                              int* __restrict__ col,
                                              float* __restrict__ wedge,
                                              const float* __restrict__ dis, int e) {
    const int xcd   = blockIdx.x & 7;
    const int chunk = blockIdx.x >> 3;
    const int lo = xcd * RNODES;
    const int hi = lo + RNODES;
    const int base = chunk * 1024 + threadIdx.x * 4;
    if (base >= e) return;                 // e % 4 == 0
    int4 d4 = *(const int4*)(dst + base);
    #pragma unroll
    for (int j = 0; j < 4; ++j) {
        int d = (&d4.x)[j];
        if (d >= lo && d < hi) {
            int s   = src[base + j];
            int pos = atomicAdd(&cursor[d], 1);
            col[pos]   = s;
            wedge[pos] = dis[s] * dis[d];
        }
    }
}

// ---------------- GEMM: H[n x 128] = X[n x 128] @ W[128 x 128] -> bf16 -------
template <typename TIN>
__global__ __launch_bounds__(256) void k_gemm(const TIN* __restrict__ X,
                                              const float* __restrict__ W,
                                              unsigned short* __restrict__ H, int n) {
    __shared__ float At[64][68];   // [k][row]
    __shared__ float Ws[64][64];   // [k][col]
    const int t  = threadIdx.x;
    const int tx = t & 15;
    const int ty = t >> 4;
    const int rb = blockIdx.x * 64;
    const int cb = blockIdx.y * 64;

    float acc[4][4] = {};

    for (int c = 0; c < 2; ++c) {
        #pragma unroll
        for (int r = 0; r < 4; ++r) {
            int f   = t + 256 * r;        // 0..1023
            int row = f >> 4;             // 0..63
            int kc  = (f & 15) << 2;      // 0..60 step 4
            int grow = rb + row;
            float4 v = make_float4(0.f, 0.f, 0.f, 0.f);
            if (grow < n) {
                if constexpr (sizeof(TIN) == 4) {
                    v = *(const float4*)((const float*)X + (size_t)grow * FD + c * 64 + kc);
                } else {
                    uint2 p = *(const uint2*)((const unsigned short*)X + (size_t)grow * FD + c * 64 + kc);
                    v.x = bf_lo(p.x); v.y = bf_hi(p.x);
                    v.z = bf_lo(p.y); v.w = bf_hi(p.y);
                }
            }
            At[kc + 0][row] = v.x;
            At[kc + 1][row] = v.y;
            At[kc + 2][row] = v.z;
            At[kc + 3][row] = v.w;
            *(float4*)&Ws[row][kc] =
                *(const float4*)(W + (size_t)(c * 64 + row) * FD + cb + kc);
        }
        __syncthreads();
        #pragma unroll 8
        for (int k = 0; k < 64; ++k) {
            float4 a = *(const float4*)&At[k][ty * 4];
            float4 b = *(const float4*)&Ws[k][tx * 4];
            acc[0][0] = fmaf(a.x, b.x, acc[0][0]);
            acc[0][1] = fmaf(a.x, b.y, acc[0][1]);
            acc[0][2] = fmaf(a.x, b.z, acc[0][2]);
            acc[0][3] = fmaf(a.x, b.w, acc[0][3]);
            acc[1][0] = fmaf(a.y, b.x, acc[1][0]);
            acc[1][1] = fmaf(a.y, b.y, acc[1][1]);
            acc[1][2] = fmaf(a.y, b.z, acc[1][2]);
            acc[1][3] = fmaf(a.y, b.w, acc[1][3]);
            acc[2][0] = fmaf(a.z, b.x, acc[2][0]);
            acc[2][1] = fmaf(a.z, b.y, acc[2][1]);
            acc[2][2] = fmaf(a.z, b.z, acc[2][2]);
            acc[2][3] = fmaf(a.z, b.w, acc[2][3]);
            acc[3][0] = fmaf(a.w, b.x, acc[3][0]);
            acc[3][1] = fmaf(a.w, b.y, acc[3][1]);
            acc[3][2] = fmaf(a.w, b.z, acc[3][2]);
            acc[3][3] = fmaf(a.w, b.w, acc[3][3]);
        }
        __syncthreads();
    }

    #pragma unroll
    for (int i = 0; i < 4; ++i) {
        int grow = rb + ty * 4 + i;
        if (grow < n) {
            uint2 p;
            p.x = bf_pack(acc[i][0], acc[i][1]);
            p.y = bf_pack(acc[i][2], acc[i][3]);
            *(uint2*)(H + (size_t)grow * FD + cb + tx * 4) = p;
        }
    }
}

// ---------------- 128-wide aggregation over bf16 rows --------------------
// TWO nodes per wave (adjacent CSR ranges); per node, ceil(deg/16) MASKED
// 16-deep gather groups (lanes past row end clamp index, weight 0) -> no
// serial tail, up to 32 independent 256B row loads in flight per wave.
// Edge metadata via wave-uniform scalar loads. fp32 accumulation.
// MODE 0: writes relu rows (bf16). MODE 1: fused dot with W3 -> outf[i].
template <int MODE>
__global__ __launch_bounds__(256) void k_agg(const unsigned short* __restrict__ h,
                                             const float* __restrict__ dis,
                                             const int* __restrict__ rp,
                                             const int* __restrict__ col,
                                             const float* __restrict__ wedge,
                                             const float* __restrict__ bias,
                                             const float* __restrict__ W3,
                                             unsigned short* __restrict__ out,
                                             float* __restrict__ outf, int n) {
    const uint32_t* h32 = (const uint32_t*)h;   // 64 words per row
    int wid  = (int)((blockIdx.x * (size_t)blockDim.x + threadIdx.x) >> 6);
    int lane = threadIdx.x & 63;
    int w2 = __builtin_amdgcn_readfirstlane(wid);
    int i0 = 2 * w2;
    if (i0 >= n) return;
    int i1 = i0 + 1;
    const bool has1 = (i1 < n);

    const int e00 = rp[i0];
    const int e01 = rp[i0 + 1];
    const int e11 = has1 ? rp[i0 + 2] : e01;

    float di0 = dis[i0];
    float di1 = has1 ? dis[i1] : 0.f;
    float2 acc0, acc1;
    {
        uint32_t su0 = h32[(size_t)i0 * 64 + lane];
        float q0 = di0 * di0;
        acc0.x = bf_lo(su0) * q0; acc0.y = bf_hi(su0) * q0;
        if (has1) {
            uint32_t su1 = h32[(size_t)i1 * 64 + lane];
            float q1 = di1 * di1;
            acc1.x = bf_lo(su1) * q1; acc1.y = bf_hi(su1) * q1;
        } else { acc1.x = acc1.y = 0.f; }
    }

    const int ng0 = (e01 - e00 + 15) >> 4;
    const int ng1 = (e11 - e01 + 15) >> 4;
    const int ng  = ng0 > ng1 ? ng0 : ng1;

    for (int g = 0; g < ng; ++g) {
        const bool do0 = (g < ng0), do1 = (g < ng1);
        int s0[16], s1[16];
        float w0_[16], w1_[16];
        uint32_t v0[16], v1[16];
        if (do0) {
            const int jb = e00 + g * 16;
            #pragma unroll
            for (int q = 0; q < 16; ++q) {
                int idx = jb + q;
                int c   = idx < e01 ? idx : e01 - 1;
                s0[q]  = col[c];
                w0_[q] = idx < e01 ? wedge[c] : 0.f;
            }
        }
        if (do1) {
            const int jb = e01 + g * 16;
            #pragma unroll
            for (int q = 0; q < 16; ++q) {
                int idx = jb + q;
                int c   = idx < e11 ? idx : e11 - 1;
                s1[q]  = col[c];
                w1_[q] = idx < e11 ? wedge[c] : 0.f;
            }
        }
        if (do0) {
            #pragma unroll
            for (int q = 0; q < 16; ++q)
                v0[q] = h32[(size_t)s0[q] * 64 + lane];
        }
        if (do1) {
            #pragma unroll
            for (int q = 0; q < 16; ++q)
                v1[q] = h32[(size_t)s1[q] * 64 + lane];
        }
        if (do0) {
            #pragma unroll
            for (int q = 0; q < 16; ++q) {
                acc0.x = fmaf(w0_[q], bf_lo(v0[q]), acc0.x);
                acc0.y = fmaf(w0_[q], bf_hi(v0[q]), acc0.y);
            }
        }
        if (do1) {
            #pragma unroll
            for (int q = 0; q < 16; ++q) {
                acc1.x = fmaf(w1_[q], bf_lo(v1[q]), acc1.x);
                acc1.y = fmaf(w1_[q], bf_hi(v1[q]), acc1.y);
            }
        }
    }

    float2 b = ((const float2*)bias)[lane];
    acc0.x = fmaxf(acc0.x + b.x, 0.f);
    acc0.y = fmaxf(acc0.y + b.y, 0.f);
    acc1.x = fmaxf(acc1.x + b.x, 0.f);
    acc1.y = fmaxf(acc1.y + b.y, 0.f);

    if (MODE == 0) {
        ((uint32_t*)out)[(size_t)i0 * 64 + lane] = bf_pack(acc0.x, acc0.y);
        if (has1)
            ((uint32_t*)out)[(size_t)i1 * 64 + lane] = bf_pack(acc1.x, acc1.y);
    } else {
        float2 w3 = ((const float2*)W3)[lane];
        float d0 = acc0.x * w3.x + acc0.y * w3.y;
        float d1 = acc1.x * w3.x + acc1.y * w3.y;
        #pragma unroll
        for (int off = 32; off; off >>= 1) {
            d0 += __shfl_xor(d0, off);
            d1 += __shfl_xor(d1, off);
        }
        if (lane == 0) {
            outf[i0] = d0;
            if (has1) outf[i1] = d1;
        }
    }
}

// ---------------- scalar aggregation + bias + sigmoid (wave per node) ----------
__global__ __launch_bounds__(256) void k_agg1(const float* __restrict__ h3,
                                              const float* __restrict__ dis,
                                              const int* __restrict__ rp,
                                              const int* __restrict__ col,
                                              const float* __restrict__ wedge,
                                              const float* __restrict__ b3,
                                              float* __restrict__ out, int n) {
    int i    = (int)((blockIdx.x * (size_t)blockDim.x + threadIdx.x) >> 6);
    int lane = threadIdx.x & 63;
    if (i >= n) return;
    float di  = dis[i];
    float acc = (lane == 0) ? di * di * h3[i] : 0.f;
    const int e0 = rp[i], e1 = rp[i + 1];
    for (int base = e0 + lane; base < e1; base += 64) {
        acc = fmaf(wedge[base], h3[col[base]], acc);
    }
    #pragma unroll
    for (int off = 32; off; off >>= 1) acc += __shfl_xor(acc, off);
    if (lane == 0) {
        float v = acc + b3[0];
        out[i] = 1.f / (1.f + expf(-v));
    }
}

// ---------------- host launch ----------------
static inline size_t alg(size_t x) { return (x + 255) & ~(size_t)255; }

extern "C" void kernel_launch(void* const* d_in, const int* in_sizes, int n_in,
                              void* d_out, int out_size, void* d_ws, size_t ws_size,
                              hipStream_t stream) {
    const float* x   = (const float*)d_in[0];
    const int*   ei  = (const int*)d_in[1];     // [2, E]
    const float* W1  = (const float*)d_in[2];
    const float* b1  = (const float*)d_in[3];
    const float* W2  = (const float*)d_in[4];
    const float* b2  = (const float*)d_in[5];
    const float* W3  = (const float*)d_in[6];
    const float* b3  = (const float*)d_in[7];
    float*       out = (float*)d_out;

    const int n = NN, e = NE;
    const int* src = ei;
    const int* dst = ei + e;

    char* w = (char*)d_ws;
    float* dis    = (float*)w;  w += alg((size_t)n * 4);
    int*   cnt    = (int*)w;    w += alg((size_t)n * 4);
    int*   rp     = (int*)w;    w += alg((size_t)(n + 1) * 4);
    int*   cursor = (int*)w;    w += alg((size_t)n * 4);
    int*   bsum   = (int*)w;    w += alg((size_t)128 * 4);
    int*   col    = (int*)w;    w += alg((size_t)e * 4);
    float* wedge  = (float*)w;  w += alg((size_t)e * 4);
    unsigned short* bufA = (unsigned short*)w; w += alg((size_t)n * FD * 2);
    unsigned short* bufB = (unsigned short*)w; w += alg((size_t)n * FD * 2);
    float* h3     = (float*)w;  w += alg((size_t)n * 4);

    hipMemsetAsync(cnt, 0, (size_t)n * 4, stream);

    const int B = 256;
    const int gN = (n + B - 1) / B;
    const int nScan = (n + 1023) / 1024;   // 98
    const int nChunk = (e + 1023) / 1024;  // 1563

    k_hist<<<nChunk * NXCD, B, 0, stream>>>(dst, cnt, e);
    k_scan1<<<nScan, 1024, 0, stream>>>(cnt, rp, bsum, n);
    k_scan2<<<1, 128, 0, stream>>>(bsum, nScan);
    k_scan3<<<gN, B, 0, stream>>>(rp, bsum, cursor, cnt, dis, n, e);
    k_fill<<<nChunk * NXCD, B, 0, stream>>>(src, dst, cursor, col, wedge, dis, e);

    dim3 gGemm((n + 63) / 64, 2);
    const int nWave2  = (n + 1) / 2;                    // two nodes per wave
    const int gWave2  = (nWave2 * 64 + B - 1) / B;      // blocks for k_agg
    const int gWave   = (n * 64 + B - 1) / B;           // wave per node (k_agg1)

    // layer 1
    k_gemm<float><<<gGemm, B, 0, stream>>>(x, W1, bufA, n);
    k_agg<0><<<gWave2, B, 0, stream>>>(bufA, dis, rp, col, wedge, b1, W3, bufB, h3, n);
    // layer 2 (+ fused layer-3 matvec)
    k_gemm<unsigned short><<<gGemm, B, 0, stream>>>(bufB, W2, bufA, n);
    k_agg<1><<<gWave2, B, 0, stream>>>(bufA, dis, rp, col, wedge, b2, W3, bufB, h3, n);
    // layer 3
    k_agg1<<<gWave, B, 0, stream>>>(h3, dis, rp, col, wedge, b3, out, n);
}